// Round 6
// baseline (28.648 us; speedup 1.0000x reference)
//
#include <hip/hip_runtime.h>
#include <hip/hip_bf16.h>

#define OUTW 2112   // 2048 + 64

typedef float          f32x4  __attribute__((ext_vector_type(4)));
typedef short          bf16x8 __attribute__((ext_vector_type(8)));
typedef unsigned short u16x8  __attribute__((ext_vector_type(8)));
typedef unsigned int   u32x4  __attribute__((ext_vector_type(4)));

// packed RNE f32x2 -> bf16x2 (compiler emits v_cvt_pk_bf16_f32)
static __device__ __forceinline__ unsigned int pk2(float a, float b) {
  union { __hip_bfloat162 h; unsigned int u; } c;
  c.h = __float22bfloat162_rn(float2{a, b});
  return c.u;
}

// raw barrier: drain LDS ops, keep global prefetch loads in flight
#define BAR() { asm volatile("s_waitcnt lgkmcnt(0)" ::: "memory");  \
                __builtin_amdgcn_s_barrier();                        \
                __builtin_amdgcn_sched_barrier(0); }

// ---------------------------------------------------------------------------
// Kernel 1: fused convert + GEMM.  Mb(bf16 256x2048) = bf16(f) @ bf16(T).
// grid 256 (4 m x 64 n), 512 thr. BM=64 BN=32 BK=128, 16 steps.
// Depth-3 REGISTER prefetch (3 load sets), 2 LDS buffers, cvt_pk packing,
// both-sides XOR swizzle, 1 raw barrier/step.
// ---------------------------------------------------------------------------
__global__ __launch_bounds__(512) void gemm_f(const float* __restrict__ f,
                                              const float* __restrict__ T,
                                              unsigned short* __restrict__ Mb) {
  __shared__ alignas(16) unsigned char smem[2][24576];  // per buf: A 16KB | B 8KB

  const int bid = blockIdx.x;
  const int m0 = (bid >> 6) * 64;
  const int n0 = (bid & 63) * 32;     // bid±64k -> same XCD: 4 m-blocks share T cols in L2
  const int t = threadIdx.x, lane = t & 63, w = t >> 6;

  const int ar0 = t >> 4;             // A rows 0..31
  const int ar1 = ar0 + 32;           // A rows 32..63
  const int ac  = t & 15;             // 16B chunk (8 fp32 -> 8 bf16)
  const int bn  = t & 31, bko = t >> 5;   // B: n 0..31, k-octet 0..15

  const float* fA0 = f + (m0 + ar0) * 2048 + ac * 8;
  const float* fA1 = f + (m0 + ar1) * 2048 + ac * 8;
  const float* fB  = T + bko * 8 * 2048 + n0 + bn;

  f32x4 rA[3][4];                     // 3 in-flight load sets (depth-3)
  float rB[3][8];

#define LOADS(sl, st) {                                                    \
    const int k0 = (st) * 128;                                             \
    rA[sl][0] = *(const f32x4*)(fA0 + k0);                                 \
    rA[sl][1] = *(const f32x4*)(fA0 + k0 + 4);                             \
    rA[sl][2] = *(const f32x4*)(fA1 + k0);                                 \
    rA[sl][3] = *(const f32x4*)(fA1 + k0 + 4);                             \
    _Pragma("unroll")                                                      \
    for (int j = 0; j < 8; ++j) rB[sl][j] = fB[(k0 + j) * 2048];           \
  }

#define PACKWRITE(bsel, sl) {                                              \
    unsigned char* Ab = smem[bsel];                                        \
    u32x4 pa0 = { pk2(rA[sl][0][0], rA[sl][0][1]),                         \
                  pk2(rA[sl][0][2], rA[sl][0][3]),                         \
                  pk2(rA[sl][1][0], rA[sl][1][1]),                         \
                  pk2(rA[sl][1][2], rA[sl][1][3]) };                       \
    u32x4 pa1 = { pk2(rA[sl][2][0], rA[sl][2][1]),                         \
                  pk2(rA[sl][2][2], rA[sl][2][3]),                         \
                  pk2(rA[sl][3][0], rA[sl][3][1]),                         \
                  pk2(rA[sl][3][2], rA[sl][3][3]) };                       \
    u32x4 pb  = { pk2(rB[sl][0], rB[sl][1]), pk2(rB[sl][2], rB[sl][3]),    \
                  pk2(rB[sl][4], rB[sl][5]), pk2(rB[sl][6], rB[sl][7]) };  \
    *(u32x4*)(Ab + ar0 * 256 + ((ac ^ (ar0 & 7)) << 4)) = pa0;             \
    *(u32x4*)(Ab + ar1 * 256 + ((ac ^ (ar1 & 7)) << 4)) = pa1;             \
    *(u32x4*)(Ab + 16384 + bn * 256 + ((bko ^ (bn & 7)) << 4)) = pb;       \
  }

  // MFMA fragment addressing (16x16x32, layouts verified R2-R5)
  const int r0 = (w >> 1) * 16 + (lane & 15);   // A row
  const int nl = (w & 1) * 16 + (lane & 15);    // B col-row
  const int hi = lane >> 4;
  const int swA = (r0 & 7) << 4, swB = (nl & 7) << 4;

  f32x4 acc0 = {0.f, 0.f, 0.f, 0.f};
  f32x4 acc1 = {0.f, 0.f, 0.f, 0.f};

  LOADS(0, 0) LOADS(1, 1) LOADS(2, 2)           // 36 loads in flight

#pragma unroll
  for (int step = 0; step < 16; ++step) {
    PACKWRITE(step & 1, step % 3)     // compiler waits exactly on set step%3's loads
    if (step < 13) LOADS(step % 3, step + 3)    // refill just-consumed set
    BAR()                             // writes visible; prefetch stays in flight
    const unsigned char* Ab = smem[step & 1];
#pragma unroll
    for (int kk = 0; kk < 4; ++kk) {
      const int cgk = (kk * 4 + hi) << 4;
      bf16x8 a = *(const bf16x8*)(Ab + r0 * 256 + (cgk ^ swA));
      bf16x8 b = *(const bf16x8*)(Ab + 16384 + nl * 256 + (cgk ^ swB));
      if (kk & 1) acc1 = __builtin_amdgcn_mfma_f32_16x16x32_bf16(a, b, acc1, 0, 0, 0);
      else        acc0 = __builtin_amdgcn_mfma_f32_16x16x32_bf16(a, b, acc0, 0, 0, 0);
    }
  }
#undef LOADS
#undef PACKWRITE

  // C/D layout: col = lane&15, row = (lane>>4)*4 + reg
  f32x4 o = acc0 + acc1;
  const int col = n0 + nl;
  const int rb  = m0 + (w >> 1) * 16 + hi * 4;
#pragma unroll
  for (int r = 0; r < 4; ++r)
    Mb[(rb + r) * 2048 + col] = (unsigned short)(pk2(o[r], o[r]) & 0xFFFF);
}

// ---------------------------------------------------------------------------
// Kernel 2: pairwise + fused f->out copy.
// o[j,b] = sum_i exp(-sum_c |M[i,b,c]-M[j,b,c]|), M in bf16.
// grid (b=64, js=8), 256 thr.
// ---------------------------------------------------------------------------
__global__ __launch_bounds__(256) void pairwise(const unsigned short* __restrict__ Mb,
                                                const float* __restrict__ f,
                                                float* __restrict__ out) {
  __shared__ alignas(16) float Ml[32][260];
  __shared__ float red[32][33];

  const int b  = blockIdx.x;
  const int js = blockIdx.y;
  const int t  = threadIdx.x;

  // fused f copy (512 blocks x 256 thr x 16B = 2 MB exactly)
  {
    const int u = (js * 64 + b) * 256 + t;
    const int row = u >> 9, c4 = (u & 511) * 4;
    *(f32x4*)(out + row * OUTW + c4) = *(const f32x4*)(f + row * 2048 + c4);
  }

  // stage M[:, b, :] transposed (bf16 -> f32)
#pragma unroll
  for (int it = 0; it < 4; ++it) {
    const int i = it * 64 + (t >> 2), c0 = (t & 3) * 8;
    u16x8 v = *(const u16x8*)(Mb + i * 2048 + b * 32 + c0);
#pragma unroll
    for (int e = 0; e < 8; ++e) {
      union { unsigned int u; float f; } q;
      q.u = ((unsigned int)(unsigned short)v[e]) << 16;
      Ml[c0 + e][i] = q.f;
    }
  }
  __syncthreads();

  const int jb = t & 7, ir = t >> 3;
  const int j0 = js * 32 + jb * 4;

  f32x4 mjA[16];
#pragma unroll
  for (int c = 0; c < 16; ++c) mjA[c] = *(const f32x4*)&Ml[c][j0];

  float opart[4] = {0.f, 0.f, 0.f, 0.f};

#pragma unroll
  for (int cell = 0; cell < 2; ++cell) {
    const int i0 = (ir + 32 * cell) * 4;
    float acc[4][4];
#pragma unroll
    for (int jj = 0; jj < 4; ++jj)
#pragma unroll
      for (int ii = 0; ii < 4; ++ii) acc[jj][ii] = 0.f;

#pragma unroll
    for (int c = 0; c < 16; ++c) {
      f32x4 mi = *(const f32x4*)&Ml[c][i0];
#pragma unroll
      for (int jj = 0; jj < 4; ++jj)
#pragma unroll
        for (int ii = 0; ii < 4; ++ii)
          acc[jj][ii] += fabsf(mjA[c][jj] - mi[ii]);
    }
    float mn = acc[0][0];
#pragma unroll
    for (int jj = 0; jj < 4; ++jj)
#pragma unroll
      for (int ii = 0; ii < 4; ++ii) mn = fminf(mn, acc[jj][ii]);

    if (!__all(mn > 30.0f)) {            // skipped tail <= 256*e^-30 ~ 2e-11
#pragma unroll
      for (int c = 16; c < 32; ++c) {
        f32x4 mj = *(const f32x4*)&Ml[c][j0];
        f32x4 mi = *(const f32x4*)&Ml[c][i0];
#pragma unroll
        for (int jj = 0; jj < 4; ++jj)
#pragma unroll
          for (int ii = 0; ii < 4; ++ii)
            acc[jj][ii] += fabsf(mj[jj] - mi[ii]);
      }
    }
#pragma unroll
    for (int jj = 0; jj < 4; ++jj)
#pragma unroll
      for (int ii = 0; ii < 4; ++ii)
        opart[jj] += __expf(-acc[jj][ii]);
  }

#pragma unroll
  for (int jj = 0; jj < 4; ++jj) red[ir][jb * 4 + jj] = opart[jj];
  __syncthreads();
  if (t < 32) {
    float s = 0.f;
#pragma unroll
    for (int r = 0; r < 32; ++r) s += red[r][t];
    out[(js * 32 + t) * OUTW + 2048 + b] = s;
  }
}

extern "C" void kernel_launch(void* const* d_in, const int* in_sizes, int n_in,
                              void* d_out, int out_size, void* d_ws, size_t ws_size,
                              hipStream_t stream) {
  const float* f = (const float*)d_in[0];
  const float* T = (const float*)d_in[1];
  float* out = (float*)d_out;

  unsigned short* Mb = (unsigned short*)d_ws;   // 1 MiB bf16 M

  gemm_f  <<<256,         512, 0, stream>>>(f, T, Mb);
  pairwise<<<dim3(64, 8), 256, 0, stream>>>(Mb, f, out);
}

// Round 7
// 26.123 us; speedup vs baseline: 1.0967x; 1.0967x over previous
//
#include <hip/hip_runtime.h>
#include <hip/hip_bf16.h>

#define OUTW 2112   // 2048 + 64

typedef float          f32x4  __attribute__((ext_vector_type(4)));
typedef short          bf16x8 __attribute__((ext_vector_type(8)));
typedef unsigned short u16x8  __attribute__((ext_vector_type(8)));

static __device__ __forceinline__ unsigned short bft(float x) {
  union { float f; unsigned int u; } v; v.f = x;
  return (unsigned short)(v.u >> 16);   // truncate to bf16 (error provably inert here)
}

// raw barrier: drain LDS ops but keep global prefetch loads in flight (avoid
// __syncthreads' vmcnt(0) drain — the m97 stall)
#define BAR() { asm volatile("s_waitcnt lgkmcnt(0)" ::: "memory");  \
                __builtin_amdgcn_s_barrier();                        \
                __builtin_amdgcn_sched_barrier(0); }

// ---------------------------------------------------------------------------
// Kernel 1: fused convert + GEMM.  Mb(bf16 256x2048) = bf16(f) @ bf16(T).
// grid 256 (4 m-blocks x 64 n-blocks), 512 thr (8 waves, 16x16 tile each).
// BM=64 BN=32 BK=128, 16 steps. Reg-stage fp32 -> cvt -> swizzled ds_write,
// depth-1 prefetch (R6's depth-3 regressed: VGPR pressure), 2 LDS buffers.
// ---------------------------------------------------------------------------
__global__ __launch_bounds__(512) void gemm_f(const float* __restrict__ f,
                                              const float* __restrict__ T,
                                              unsigned short* __restrict__ Mb) {
  __shared__ alignas(16) unsigned char smem[2][24576];  // per buf: A 16KB | B 8KB

  const int bid = blockIdx.x;
  const int m0 = (bid >> 6) * 64;
  const int n0 = (bid & 63) * 32;     // bid±64k -> same XCD: 4 m-blocks share T cols in L2
  const int t = threadIdx.x, lane = t & 63, w = t >> 6;

  const int ar0 = t >> 4;             // A rows 0..31
  const int ar1 = ar0 + 32;           // A rows 32..63
  const int ac  = t & 15;             // 16B chunk (8 fp32 -> 8 bf16)
  const int bn  = t & 31, bko = t >> 5;   // B: n 0..31, k-octet 0..15

  const float* fA0 = f + (m0 + ar0) * 2048 + ac * 8;
  const float* fA1 = f + (m0 + ar1) * 2048 + ac * 8;
  const float* fB  = T + bko * 8 * 2048 + n0 + bn;

  f32x4 rA[4];
  float rB[8];

#define LOADS(st) {                                                        \
    const int k0 = (st) * 128;                                             \
    rA[0] = *(const f32x4*)(fA0 + k0);  rA[1] = *(const f32x4*)(fA0 + k0 + 4); \
    rA[2] = *(const f32x4*)(fA1 + k0);  rA[3] = *(const f32x4*)(fA1 + k0 + 4); \
    _Pragma("unroll")                                                      \
    for (int j = 0; j < 8; ++j) rB[j] = fB[(k0 + j) * 2048];               \
  }

#define PACKWRITE(bsel) {                                                  \
    unsigned char* Ab = smem[bsel];                                        \
    u16x8 pa0 = { bft(rA[0][0]), bft(rA[0][1]), bft(rA[0][2]), bft(rA[0][3]), \
                  bft(rA[1][0]), bft(rA[1][1]), bft(rA[1][2]), bft(rA[1][3]) }; \
    u16x8 pa1 = { bft(rA[2][0]), bft(rA[2][1]), bft(rA[2][2]), bft(rA[2][3]), \
                  bft(rA[3][0]), bft(rA[3][1]), bft(rA[3][2]), bft(rA[3][3]) }; \
    u16x8 pb  = { bft(rB[0]), bft(rB[1]), bft(rB[2]), bft(rB[3]),          \
                  bft(rB[4]), bft(rB[5]), bft(rB[6]), bft(rB[7]) };        \
    *(u16x8*)(Ab + ar0 * 256 + ((ac ^ (ar0 & 7)) << 4)) = pa0;             \
    *(u16x8*)(Ab + ar1 * 256 + ((ac ^ (ar1 & 7)) << 4)) = pa1;             \
    *(u16x8*)(Ab + 16384 + bn * 256 + ((bko ^ (bn & 7)) << 4)) = pb;       \
  }

  // MFMA fragment addressing (16x16x32, layouts verified R2-R5)
  const int r0 = (w >> 1) * 16 + (lane & 15);   // A row
  const int nl = (w & 1) * 16 + (lane & 15);    // B col-row
  const int hi = lane >> 4;
  const int swA = (r0 & 7) << 4, swB = (nl & 7) << 4;

  f32x4 acc0 = {0.f, 0.f, 0.f, 0.f};
  f32x4 acc1 = {0.f, 0.f, 0.f, 0.f};

  LOADS(0)
#pragma unroll
  for (int step = 0; step < 16; ++step) {
    PACKWRITE(step & 1)                 // compiler inserts exact vmcnt before pack
    if (step < 15) LOADS(step + 1)      // prefetch stays in flight across BAR
    BAR()                               // writes visible; reads of buf done 2 steps ago
    const unsigned char* Ab = smem[step & 1];
#pragma unroll
    for (int kk = 0; kk < 4; ++kk) {
      const int cgk = (kk * 4 + hi) << 4;
      bf16x8 a = *(const bf16x8*)(Ab + r0 * 256 + (cgk ^ swA));
      bf16x8 b = *(const bf16x8*)(Ab + 16384 + nl * 256 + (cgk ^ swB));
      if (kk & 1) acc1 = __builtin_amdgcn_mfma_f32_16x16x32_bf16(a, b, acc1, 0, 0, 0);
      else        acc0 = __builtin_amdgcn_mfma_f32_16x16x32_bf16(a, b, acc0, 0, 0, 0);
    }
  }
#undef LOADS
#undef PACKWRITE

  // C/D layout: col = lane&15, row = (lane>>4)*4 + reg
  f32x4 o = acc0 + acc1;
  const int col = n0 + nl;
  const int rb  = m0 + (w >> 1) * 16 + hi * 4;
#pragma unroll
  for (int r = 0; r < 4; ++r)
    Mb[(rb + r) * 2048 + col] = bft(o[r]);
}

// ---------------------------------------------------------------------------
// Kernel 2: pairwise + fused f->out copy.
// o[j,b] = sum_i exp(-sum_c |M[i,b,c]-M[j,b,c]|), M in bf16.
// grid (b=64, js=8), 256 thr.
// ---------------------------------------------------------------------------
__global__ __launch_bounds__(256) void pairwise(const unsigned short* __restrict__ Mb,
                                                const float* __restrict__ f,
                                                float* __restrict__ out) {
  __shared__ alignas(16) float Ml[32][260];
  __shared__ float red[32][33];

  const int b  = blockIdx.x;
  const int js = blockIdx.y;
  const int t  = threadIdx.x;

  // fused f copy (512 blocks x 256 thr x 16B = 2 MB exactly)
  {
    const int u = (js * 64 + b) * 256 + t;
    const int row = u >> 9, c4 = (u & 511) * 4;
    *(f32x4*)(out + row * OUTW + c4) = *(const f32x4*)(f + row * 2048 + c4);
  }

  // stage M[:, b, :] transposed (bf16 -> f32)
#pragma unroll
  for (int it = 0; it < 4; ++it) {
    const int i = it * 64 + (t >> 2), c0 = (t & 3) * 8;
    u16x8 v = *(const u16x8*)(Mb + i * 2048 + b * 32 + c0);
#pragma unroll
    for (int e = 0; e < 8; ++e) {
      union { unsigned int u; float f; } q;
      q.u = ((unsigned int)(unsigned short)v[e]) << 16;
      Ml[c0 + e][i] = q.f;
    }
  }
  __syncthreads();

  const int jb = t & 7, ir = t >> 3;
  const int j0 = js * 32 + jb * 4;

  f32x4 mjA[16];
#pragma unroll
  for (int c = 0; c < 16; ++c) mjA[c] = *(const f32x4*)&Ml[c][j0];

  float opart[4] = {0.f, 0.f, 0.f, 0.f};

#pragma unroll
  for (int cell = 0; cell < 2; ++cell) {
    const int i0 = (ir + 32 * cell) * 4;
    float acc[4][4];
#pragma unroll
    for (int jj = 0; jj < 4; ++jj)
#pragma unroll
      for (int ii = 0; ii < 4; ++ii) acc[jj][ii] = 0.f;

#pragma unroll
    for (int c = 0; c < 16; ++c) {
      f32x4 mi = *(const f32x4*)&Ml[c][i0];
#pragma unroll
      for (int jj = 0; jj < 4; ++jj)
#pragma unroll
        for (int ii = 0; ii < 4; ++ii)
          acc[jj][ii] += fabsf(mjA[c][jj] - mi[ii]);
    }
    float mn = acc[0][0];
#pragma unroll
    for (int jj = 0; jj < 4; ++jj)
#pragma unroll
      for (int ii = 0; ii < 4; ++ii) mn = fminf(mn, acc[jj][ii]);

    if (!__all(mn > 30.0f)) {            // skipped tail <= 256*e^-30 ~ 2e-11
#pragma unroll
      for (int c = 16; c < 32; ++c) {
        f32x4 mj = *(const f32x4*)&Ml[c][j0];
        f32x4 mi = *(const f32x4*)&Ml[c][i0];
#pragma unroll
        for (int jj = 0; jj < 4; ++jj)
#pragma unroll
          for (int ii = 0; ii < 4; ++ii)
            acc[jj][ii] += fabsf(mj[jj] - mi[ii]);
      }
    }
#pragma unroll
    for (int jj = 0; jj < 4; ++jj)
#pragma unroll
      for (int ii = 0; ii < 4; ++ii)
        opart[jj] += __expf(-acc[jj][ii]);
  }

#pragma unroll
  for (int jj = 0; jj < 4; ++jj) red[ir][jb * 4 + jj] = opart[jj];
  __syncthreads();
  if (t < 32) {
    float s = 0.f;
#pragma unroll
    for (int r = 0; r < 32; ++r) s += red[r][t];
    out[(js * 32 + t) * OUTW + 2048 + b] = s;
  }
}

extern "C" void kernel_launch(void* const* d_in, const int* in_sizes, int n_in,
                              void* d_out, int out_size, void* d_ws, size_t ws_size,
                              hipStream_t stream) {
  const float* f = (const float*)d_in[0];
  const float* T = (const float*)d_in[1];
  float* out = (float*)d_out;

  unsigned short* Mb = (unsigned short*)d_ws;   // 1 MiB bf16 M

  gemm_f  <<<256,         512, 0, stream>>>(f, T, Mb);
  pairwise<<<dim3(64, 8), 256, 0, stream>>>(Mb, f, out);
}